// Round 7
// baseline (396.838 us; speedup 1.0000x reference)
//
#include <hip/hip_runtime.h>
#include <stdint.h>

typedef unsigned short u16;
typedef __attribute__((ext_vector_type(8))) short bf16x8;
typedef __attribute__((ext_vector_type(4))) float f32x4;

#define LOG2E 1.44269504088896340736f

__device__ __forceinline__ float bf2f(u16 u) {
  union { uint32_t u; float f; } v; v.u = ((uint32_t)u) << 16; return v.f;
}
__device__ __forceinline__ u16 f2bf(float f) {
  union { float f; uint32_t u; } v; v.f = f;
  uint32_t r = v.u + 0x7fffu + ((v.u >> 16) & 1u);
  return (u16)(r >> 16);
}

// async global->LDS, 16B per lane; lds ptr must be wave-uniform base (HW adds lane*16)
__device__ __forceinline__ void gl_lds16(const u16* g, u16* l) {
  __builtin_amdgcn_global_load_lds((const __attribute__((address_space(1))) void*)g,
                                   (__attribute__((address_space(3))) void*)l, 16, 0, 0);
}

// ---------------- x: fp32 -> bf16 ----------------
__global__ __launch_bounds__(256) void k_cvt_x(const float* __restrict__ x,
                                               u16* __restrict__ xb) {
  const int i = blockIdx.x * 256 + threadIdx.x;
  float4 v = ((const float4*)x)[i];
  ushort4 o;
  o.x = f2bf(v.x); o.y = f2bf(v.y); o.z = f2bf(v.z); o.w = f2bf(v.w);
  ((ushort4*)xb)[i] = o;
}

// ---------------- transpose fp32 -> bf16 (64x64 tile via LDS, XOR-swizzled) ----------------
__device__ __forceinline__ void transpose64f(const float* src, int sstride,
                                             u16* dst, int dstride,
                                             float scale, u16* tile /*64*80*/) {
  const int tid = threadIdx.x;
  const int row = tid >> 3, seg = tid & 7;
#pragma unroll
  for (int p = 0; p < 2; ++p) {
    int rr = p * 32 + row;
    int rw = rr ^ (seg * 8);
    float4 a = *(const float4*)(src + rr * sstride + seg * 8);
    float4 b = *(const float4*)(src + rr * sstride + seg * 8 + 4);
    tile[(seg * 8 + 0) * 80 + rw] = f2bf(a.x * scale);
    tile[(seg * 8 + 1) * 80 + rw] = f2bf(a.y * scale);
    tile[(seg * 8 + 2) * 80 + rw] = f2bf(a.z * scale);
    tile[(seg * 8 + 3) * 80 + rw] = f2bf(a.w * scale);
    tile[(seg * 8 + 4) * 80 + rw] = f2bf(b.x * scale);
    tile[(seg * 8 + 5) * 80 + rw] = f2bf(b.y * scale);
    tile[(seg * 8 + 6) * 80 + rw] = f2bf(b.z * scale);
    tile[(seg * 8 + 7) * 80 + rw] = f2bf(b.w * scale);
  }
  __syncthreads();
#pragma unroll
  for (int p = 0; p < 2; ++p) {
    int rr = p * 32 + row;
    int sw = (seg ^ ((rr >> 3) & 7)) * 8;
    *(uint4*)(dst + rr * dstride + seg * 8) = *(uint4*)(tile + rr * 80 + sw);
  }
}

// Wq|Wk|Wv (each 256x2048 fp32) -> Wt (6144x256 bf16), q/k scaled 0.25
__global__ __launch_bounds__(256) void k_transpose_wqkv(const float* __restrict__ Wq,
                                                        const float* __restrict__ Wk,
                                                        const float* __restrict__ Wv,
                                                        u16* __restrict__ Wt) {
  __shared__ u16 tile[64 * 80];
  const int o0 = blockIdx.x * 64, i0 = blockIdx.y * 64;
  const float* src; float scale = 0.25f; int oc0 = o0;
  if (o0 < 2048)      { src = Wq; }
  else if (o0 < 4096) { src = Wk; oc0 = o0 - 2048; }
  else                { src = Wv; oc0 = o0 - 4096; scale = 1.0f; }
  transpose64f(src + i0 * 2048 + oc0, 2048, Wt + o0 * 256 + i0, 256, scale, tile);
}

// Wu (2048x256 fp32) -> Wut (256x2048 bf16)
__global__ __launch_bounds__(256) void k_transpose_wu(const float* __restrict__ Wu,
                                                      u16* __restrict__ Wut) {
  __shared__ u16 tile[64 * 80];
  const int c0 = blockIdx.x * 64, r0 = blockIdx.y * 64;
  transpose64f(Wu + r0 * 256 + c0, 256, Wut + c0 * 2048 + r0, 2048, 1.0f, tile);
}

// ---------------- QKV projection GEMM (V written transposed into vt directly) --------
// A = xb (8192x256 bf16), Bt = Wt (6144x256), C = qkv rows for n<4096 (Q|K),
// V region (n>=4096) stored as vt (b,h,d,t) via packed 8B stores (4 consecutive tokens).
__global__ __launch_bounds__(256) void k_gemm_qkv(const u16* __restrict__ A,
                                                  const u16* __restrict__ Bt,
                                                  u16* __restrict__ C,
                                                  u16* __restrict__ vt) {
  __shared__ u16 As[128 * 32];
  __shared__ u16 Bs[128 * 32];
  const int m0 = blockIdx.y * 128, n0 = blockIdx.x * 128;
  const int tid = threadIdx.x, w = tid >> 6, lane = tid & 63;
  const int q = lane >> 4, r = lane & 15;
  const int wm = (w >> 1) * 64, wn = (w & 1) * 64;
  const int bo0 = w * 2048 + lane * 16;
  const int row0 = bo0 >> 6, col0 = (bo0 & 63) >> 1;
  const int bo1 = bo0 + 1024;
  const int row1 = bo1 >> 6, col1 = (bo1 & 63) >> 1;
  f32x4 acc[4][4] = {};
  for (int kt = 0; kt < 256; kt += 32) {
    __syncthreads();
    gl_lds16(A + (m0 + row0) * 256 + kt + col0, As + w * 1024);
    gl_lds16(A + (m0 + row1) * 256 + kt + col1, As + w * 1024 + 512);
    gl_lds16(Bt + (n0 + row0) * 256 + kt + col0, Bs + w * 1024);
    gl_lds16(Bt + (n0 + row1) * 256 + kt + col1, Bs + w * 1024 + 512);
    __syncthreads();
    bf16x8 af[4], bf[4];
#pragma unroll
    for (int mb = 0; mb < 4; ++mb) af[mb] = *(const bf16x8*)(As + (wm + mb * 16 + r) * 32 + q * 8);
#pragma unroll
    for (int nb = 0; nb < 4; ++nb) bf[nb] = *(const bf16x8*)(Bs + (wn + nb * 16 + r) * 32 + q * 8);
#pragma unroll
    for (int mb = 0; mb < 4; ++mb)
#pragma unroll
      for (int nb = 0; nb < 4; ++nb)
        acc[mb][nb] = __builtin_amdgcn_mfma_f32_16x16x32_bf16(af[mb], bf[nb], acc[mb][nb], 0, 0, 0);
  }
  if (n0 < 4096) {
    // Q|K: row-major into qkv
#pragma unroll
    for (int mb = 0; mb < 4; ++mb)
#pragma unroll
      for (int nb = 0; nb < 4; ++nb) {
        const int nn = n0 + wn + nb * 16 + r;
#pragma unroll
        for (int reg = 0; reg < 4; ++reg) {
          const int mm = m0 + wm + mb * 16 + q * 4 + reg;
          C[(size_t)mm * 6144 + nn] = f2bf(acc[mb][nb][reg]);
        }
      }
  } else {
    // V: transposed into vt (b,h,d,t); 4 consecutive tokens pack into one 8B store
#pragma unroll
    for (int mb = 0; mb < 4; ++mb)
#pragma unroll
      for (int nb = 0; nb < 4; ++nb) {
        const int hd = n0 - 4096 + wn + nb * 16 + r;     // h*256+d
        const int mm0 = m0 + wm + mb * 16 + q * 4;       // base token, 4 consecutive
        const int bb = mm0 >> 10, t = mm0 & 1023;
        uint2 val;
        val.x = (uint32_t)f2bf(acc[mb][nb][0]) | ((uint32_t)f2bf(acc[mb][nb][1]) << 16);
        val.y = (uint32_t)f2bf(acc[mb][nb][2]) | ((uint32_t)f2bf(acc[mb][nb][3]) << 16);
        *(uint2*)(vt + ((size_t)(bb * 2048 + hd)) * 1024 + t) = val;
      }
  }
}

// ---------------- fused flash attention (S^T / O^T, 32 q-rows/wave, fixed-ref softmax,
//                  register-prefetch software pipeline) ----------------
__global__ __launch_bounds__(256, 2) void k_attn(const u16* __restrict__ qkv,
                                                 const u16* __restrict__ vt,
                                                 u16* __restrict__ att) {
  __shared__ u16 smem[17152];   // K frag [0,8192) | V frag [8192,16384) | Os overlay
  const int blk = blockIdx.x;
  const int qt = blk >> 6, bh = blk & 63;       // bh-major: XCD = h -> L2 chunk sharing
  const int b = bh >> 3, h = bh & 7;
  const int tid = threadIdx.x, w = tid >> 6, lane = tid & 63;
  const int q = lane >> 4, r = lane & 15;
  const int t0 = qt * 128 + w * 32;

  // Q B-fragments (two row groups), loaded once
  const u16* QgA = qkv + ((size_t)(b * 1024 + t0 + r)) * 6144 + h * 256;
  const u16* QgB = QgA + (size_t)16 * 6144;
  bf16x8 qfA[8], qfB[8];
#pragma unroll
  for (int kc = 0; kc < 8; ++kc) {
    qfA[kc] = *(const bf16x8*)(QgA + kc * 32 + q * 8);
    qfB[kc] = *(const bf16x8*)(QgB + kc * 32 + q * 8);
  }

  float lA = 0.0f, lB = 0.0f;   // per-lane partial softmax denominators
  f32x4 oA[16] = {}, oB[16] = {};

  const u16* Kg = qkv + (size_t)b * 1024 * 6144 + 2048 + h * 256;
  const u16* Vg = vt + (size_t)(b * 8 + h) * 256 * 1024;

  const int kc_s = (tid & 31) >> 2, kq_s = tid & 3;   // K staging decode
  const int db_s = tid >> 4, vr_s = tid & 15;          // V staging decode

  // ---- prefetch chunk 0 into registers
  uint4 kpre[4], vpre[4];
#pragma unroll
  for (int p = 0; p < 4; ++p) {
    int key = p * 8 + (tid >> 5);
    kpre[p] = *(const uint4*)(Kg + (size_t)key * 6144 + (tid & 31) * 8);
    vpre[p] = *(const uint4*)(Vg + (size_t)tid * 1024 + p * 8);
  }

  for (int sc = 0; sc < 1024; sc += 32) {
    __syncthreads();   // readers of previous chunk done
    // ---- write prefetched K into fragment-major swizzled LDS
#pragma unroll
    for (int p = 0; p < 4; ++p) {
      int key = p * 8 + (tid >> 5);
      int sb = key >> 4, kr = key & 15;
      int unit = (kc_s * 2 + sb) * 64 + kq_s * 16 + ((kr + kq_s + kc_s * 4) & 15);
      *(uint4*)(smem + unit * 8) = kpre[p];
    }
    // ---- write prefetched V^T
#pragma unroll
    for (int p = 0; p < 4; ++p) {
      int unit = db_s * 64 + p * 16 + ((vr_s + p) & 15);
      *(uint4*)(smem + 8192 + unit * 8) = vpre[p];
    }
    __syncthreads();

    // ---- issue next chunk's global loads (overlap with compute below)
    if (sc + 32 < 1024) {
#pragma unroll
      for (int p = 0; p < 4; ++p) {
        int key = p * 8 + (tid >> 5);
        kpre[p] = *(const uint4*)(Kg + (size_t)(sc + 32 + key) * 6144 + (tid & 31) * 8);
        vpre[p] = *(const uint4*)(Vg + (size_t)tid * 1024 + sc + 32 + p * 8);
      }
    }

    // ---- S^T = K Q^T for both row groups; each K fragment feeds 2 MFMAs
    f32x4 s0A = {}, s1A = {}, s0B = {}, s1B = {};
#pragma unroll
    for (int kc = 0; kc < 8; ++kc) {
      bf16x8 k0 = *(const bf16x8*)(smem + ((kc * 2 + 0) * 64 + q * 16 + ((r + q + kc * 4) & 15)) * 8);
      bf16x8 k1 = *(const bf16x8*)(smem + ((kc * 2 + 1) * 64 + q * 16 + ((r + q + kc * 4) & 15)) * 8);
      s0A = __builtin_amdgcn_mfma_f32_16x16x32_bf16(k0, qfA[kc], s0A, 0, 0, 0);
      s1A = __builtin_amdgcn_mfma_f32_16x16x32_bf16(k1, qfA[kc], s1A, 0, 0, 0);
      s0B = __builtin_amdgcn_mfma_f32_16x16x32_bf16(k0, qfB[kc], s0B, 0, 0, 0);
      s1B = __builtin_amdgcn_mfma_f32_16x16x32_bf16(k1, qfB[kc], s1B, 0, 0, 0);
    }

    // ---- fixed-reference softmax + P^T fragment via packed shuffles
    union { bf16x8 v; u16 e[8]; } pfA, pfB;
    {
      float pa[4], pb[4];
#pragma unroll
      for (int reg = 0; reg < 4; ++reg) {
        pa[reg] = exp2f(s0A[reg] * LOG2E);
        pb[reg] = exp2f(s1A[reg] * LOG2E);
        lA += pa[reg] + pb[reg];
      }
      uint32_t pk[4];
#pragma unroll
      for (int reg = 0; reg < 4; ++reg)
        pk[reg] = (uint32_t)f2bf(pa[reg]) | ((uint32_t)f2bf(pb[reg]) << 16);
      const int srcA = ((q & 1) << 5) + r, srcB = srcA + 16;
      uint32_t tt[8];
#pragma unroll
      for (int reg = 0; reg < 4; ++reg) tt[reg] = (uint32_t)__shfl((int)pk[reg], srcA);
#pragma unroll
      for (int reg = 0; reg < 4; ++reg) tt[4 + reg] = (uint32_t)__shfl((int)pk[reg], srcB);
      const bool hi = (q >= 2);
#pragma unroll
      for (int j = 0; j < 8; ++j)
        pfA.e[j] = hi ? (u16)(tt[j] >> 16) : (u16)(tt[j] & 0xffffu);
    }
    {
      float pa[4], pb[4];
#pragma unroll
      for (int reg = 0; reg < 4; ++reg) {
        pa[reg] = exp2f(s0B[reg] * LOG2E);
        pb[reg] = exp2f(s1B[reg] * LOG2E);
        lB += pa[reg] + pb[reg];
      }
      uint32_t pk[4];
#pragma unroll
      for (int reg = 0; reg < 4; ++reg)
        pk[reg] = (uint32_t)f2bf(pa[reg]) | ((uint32_t)f2bf(pb[reg]) << 16);
      const int srcA = ((q & 1) << 5) + r, srcB = srcA + 16;
      uint32_t tt[8];
#pragma unroll
      for (int reg = 0; reg < 4; ++reg) tt[reg] = (uint32_t)__shfl((int)pk[reg], srcA);
#pragma unroll
      for (int reg = 0; reg < 4; ++reg) tt[4 + reg] = (uint32_t)__shfl((int)pk[reg], srcB);
      const bool hi = (q >= 2);
#pragma unroll
      for (int j = 0; j < 8; ++j)
        pfB.e[j] = hi ? (u16)(tt[j] >> 16) : (u16)(tt[j] & 0xffffu);
    }

    // ---- O^T += V^T P^T; each V fragment feeds 2 MFMAs
#pragma unroll
    for (int db = 0; db < 16; ++db) {
      bf16x8 vf = *(const bf16x8*)(smem + 8192 + (db * 64 + q * 16 + ((r + q) & 15)) * 8);
      oA[db] = __builtin_amdgcn_mfma_f32_16x16x32_bf16(vf, pfA.v, oA[db], 0, 0, 0);
      oB[db] = __builtin_amdgcn_mfma_f32_16x16x32_bf16(vf, pfB.v, oB[db], 0, 0, 0);
    }
  }

  // ---- final l reduction (once): lanes r, r+16, r+32, r+48 share qrow r
  lA += __shfl_xor(lA, 16); lA += __shfl_xor(lA, 32);
  lB += __shfl_xor(lB, 16); lB += __shfl_xor(lB, 32);
  float rlA = 1.0f / lA, rlB = 1.0f / lB;

  // ---- epilogue: two passes through per-wave Os buffer (16 rows x pitch 268)
  __syncthreads();  // all waves done with K/V region before overlay
  u16* Os = smem + w * 4288;
#pragma unroll
  for (int pass = 0; pass < 2; ++pass) {
    const f32x4* o = pass ? oB : oA;
    const float rl = pass ? rlB : rlA;
    const int tb = t0 + pass * 16;
    __syncthreads();  // prior pass's reads done before overwrite
#pragma unroll
    for (int db = 0; db < 16; ++db) {
      uint32_t lo = (uint32_t)f2bf(o[db][0] * rl) | ((uint32_t)f2bf(o[db][1] * rl) << 16);
      uint32_t hi2 = (uint32_t)f2bf(o[db][2] * rl) | ((uint32_t)f2bf(o[db][3] * rl) << 16);
      uint2 val; val.x = lo; val.y = hi2;
      *(uint2*)(Os + r * 268 + db * 16 + q * 4) = val;
    }
    asm volatile("s_waitcnt lgkmcnt(0)" ::: "memory");
    u16* Ag = att + ((size_t)(b * 1024 + tb)) * 2048 + h * 256;
#pragma unroll
    for (int p = 0; p < 8; ++p) {
      int idx = (p * 64 + lane) * 8;
      int row = idx >> 8, col = idx & 255;
      *(uint4*)(Ag + (size_t)row * 2048 + col) = *(uint4*)(Os + row * 268 + col);
    }
  }
}

// ---------------- unify GEMM + bias (64x64 tiles, 512 blocks = 2/CU) ----------------
__global__ __launch_bounds__(256) void k_gemm_out(const u16* __restrict__ A,
                                                  const u16* __restrict__ Bt,
                                                  const float* __restrict__ bu,
                                                  float* __restrict__ C) {
  __shared__ u16 As[64 * 32];
  __shared__ u16 Bs[64 * 32];
  const int m0 = blockIdx.y * 64, n0 = blockIdx.x * 64;
  const int tid = threadIdx.x, w = tid >> 6, lane = tid & 63;
  const int q = lane >> 4, r = lane & 15;
  const int wm = (w >> 1) * 32, wn = (w & 1) * 32;
  const int bo = w * 1024 + lane * 16;       // byte offset within 64x32 tile
  const int rw = bo >> 6, cl = (bo & 63) >> 1;
  f32x4 acc[2][2] = {};
  for (int kt = 0; kt < 2048; kt += 32) {
    __syncthreads();
    gl_lds16(A + (size_t)(m0 + rw) * 2048 + kt + cl, As + w * 512);
    gl_lds16(Bt + (size_t)(n0 + rw) * 2048 + kt + cl, Bs + w * 512);
    __syncthreads();
    bf16x8 af[2], bf[2];
#pragma unroll
    for (int mb = 0; mb < 2; ++mb) af[mb] = *(const bf16x8*)(As + (wm + mb * 16 + r) * 32 + q * 8);
#pragma unroll
    for (int nb = 0; nb < 2; ++nb) bf[nb] = *(const bf16x8*)(Bs + (wn + nb * 16 + r) * 32 + q * 8);
#pragma unroll
    for (int mb = 0; mb < 2; ++mb)
#pragma unroll
      for (int nb = 0; nb < 2; ++nb)
        acc[mb][nb] = __builtin_amdgcn_mfma_f32_16x16x32_bf16(af[mb], bf[nb], acc[mb][nb], 0, 0, 0);
  }
  float bias[2];
#pragma unroll
  for (int nb = 0; nb < 2; ++nb) bias[nb] = bu[n0 + wn + nb * 16 + r];
#pragma unroll
  for (int mb = 0; mb < 2; ++mb)
#pragma unroll
    for (int nb = 0; nb < 2; ++nb) {
      const int nn = n0 + wn + nb * 16 + r;
#pragma unroll
      for (int reg = 0; reg < 4; ++reg) {
        const int mm = m0 + wm + mb * 16 + q * 4 + reg;
        C[(size_t)mm * 256 + nn] = acc[mb][nb][reg] + bias[nb];
      }
    }
}

extern "C" void kernel_launch(void* const* d_in, const int* in_sizes, int n_in,
                              void* d_out, int out_size, void* d_ws, size_t ws_size,
                              hipStream_t stream) {
  const float* x  = (const float*)d_in[0];
  const float* Wq = (const float*)d_in[1];
  const float* Wk = (const float*)d_in[2];
  const float* Wv = (const float*)d_in[3];
  const float* Wu = (const float*)d_in[4];
  const float* bu = (const float*)d_in[5];
  float* outp = (float*)d_out;

  char* ws = (char*)d_ws;
  u16* qkv   = (u16*)(ws);                          // 100663296 (V third unused)
  u16* vt    = (u16*)(ws + 100663296);              // 33554432
  u16* attb  = (u16*)(ws + 134217728);              // 33554432
  u16* wqkvt = (u16*)(ws + 167772160);              // 3145728
  u16* wut   = (u16*)(ws + 170917888);              // 1048576
  u16* xb    = (u16*)(ws + 171966464);              // 4194304
  (void)in_sizes; (void)n_in; (void)out_size; (void)ws_size;

  dim3 blk(256);
  k_cvt_x<<<dim3(2048), blk, 0, stream>>>(x, xb);
  k_transpose_wqkv<<<dim3(96, 4), blk, 0, stream>>>(Wq, Wk, Wv, wqkvt);
  k_transpose_wu<<<dim3(4, 32), blk, 0, stream>>>(Wu, wut);
  k_gemm_qkv<<<dim3(48, 64), blk, 0, stream>>>(xb, wqkvt, qkv, vt);
  k_attn<<<dim3(512), blk, 0, stream>>>(qkv, vt, attb);
  k_gemm_out<<<dim3(4, 128), blk, 0, stream>>>(attb, wut, bu, outp);
}

// Round 8
// 267.818 us; speedup vs baseline: 1.4817x; 1.4817x over previous
//
#include <hip/hip_runtime.h>
#include <stdint.h>

typedef unsigned short u16;
typedef __attribute__((ext_vector_type(8))) short bf16x8;
typedef __attribute__((ext_vector_type(4))) float f32x4;

#define LOG2E 1.44269504088896340736f

__device__ __forceinline__ float bf2f(u16 u) {
  union { uint32_t u; float f; } v; v.u = ((uint32_t)u) << 16; return v.f;
}
__device__ __forceinline__ u16 f2bf(float f) {
  union { float f; uint32_t u; } v; v.f = f;
  uint32_t r = v.u + 0x7fffu + ((v.u >> 16) & 1u);
  return (u16)(r >> 16);
}

// async global->LDS, 16B per lane; lds ptr must be wave-uniform base (HW adds lane*16)
__device__ __forceinline__ void gl_lds16(const u16* g, u16* l) {
  __builtin_amdgcn_global_load_lds((const __attribute__((address_space(1))) void*)g,
                                   (__attribute__((address_space(3))) void*)l, 16, 0, 0);
}

// ---------------- transpose fp32 -> bf16 (64x64 tile via LDS, XOR-swizzled) ----------------
__device__ __forceinline__ void transpose64f(const float* src, int sstride,
                                             u16* dst, int dstride,
                                             float scale, u16* tile /*64*80*/) {
  const int tid = threadIdx.x;
  const int row = tid >> 3, seg = tid & 7;
#pragma unroll
  for (int p = 0; p < 2; ++p) {
    int rr = p * 32 + row;
    int rw = rr ^ (seg * 8);
    float4 a = *(const float4*)(src + rr * sstride + seg * 8);
    float4 b = *(const float4*)(src + rr * sstride + seg * 8 + 4);
    tile[(seg * 8 + 0) * 80 + rw] = f2bf(a.x * scale);
    tile[(seg * 8 + 1) * 80 + rw] = f2bf(a.y * scale);
    tile[(seg * 8 + 2) * 80 + rw] = f2bf(a.z * scale);
    tile[(seg * 8 + 3) * 80 + rw] = f2bf(a.w * scale);
    tile[(seg * 8 + 4) * 80 + rw] = f2bf(b.x * scale);
    tile[(seg * 8 + 5) * 80 + rw] = f2bf(b.y * scale);
    tile[(seg * 8 + 6) * 80 + rw] = f2bf(b.z * scale);
    tile[(seg * 8 + 7) * 80 + rw] = f2bf(b.w * scale);
  }
  __syncthreads();
#pragma unroll
  for (int p = 0; p < 2; ++p) {
    int rr = p * 32 + row;
    int sw = (seg ^ ((rr >> 3) & 7)) * 8;
    *(uint4*)(dst + rr * dstride + seg * 8) = *(uint4*)(tile + rr * 80 + sw);
  }
}

// ---------------- fused prep: x cvt (blocks 0..2047) | Wqkv^T (2048..2431) | Wu^T (2432..2559)
__global__ __launch_bounds__(256) void k_prep(const float* __restrict__ x,
                                              const float* __restrict__ Wq,
                                              const float* __restrict__ Wk,
                                              const float* __restrict__ Wv,
                                              const float* __restrict__ Wu,
                                              u16* __restrict__ xb,
                                              u16* __restrict__ Wt,
                                              u16* __restrict__ Wut) {
  __shared__ u16 tile[64 * 80];
  const int bx = blockIdx.x;
  if (bx < 2048) {
    const int i = bx * 256 + threadIdx.x;
    float4 v = ((const float4*)x)[i];
    ushort4 o;
    o.x = f2bf(v.x); o.y = f2bf(v.y); o.z = f2bf(v.z); o.w = f2bf(v.w);
    ((ushort4*)xb)[i] = o;
  } else if (bx < 2432) {
    const int idx = bx - 2048;
    const int o0 = (idx % 96) * 64, i0 = (idx / 96) * 64;
    const float* src; float scale = 0.25f; int oc0 = o0;
    if (o0 < 2048)      { src = Wq; }
    else if (o0 < 4096) { src = Wk; oc0 = o0 - 2048; }
    else                { src = Wv; oc0 = o0 - 4096; scale = 1.0f; }
    transpose64f(src + i0 * 2048 + oc0, 2048, Wt + o0 * 256 + i0, 256, scale, tile);
  } else {
    const int idx = bx - 2432;
    const int c0 = (idx % 4) * 64, r0 = (idx / 4) * 64;
    transpose64f(Wu + r0 * 256 + c0, 256, Wut + c0 * 2048 + r0, 2048, 1.0f, tile);
  }
}

// ---------------- QKV projection GEMM (V written transposed into vt directly) --------
__global__ __launch_bounds__(256) void k_gemm_qkv(const u16* __restrict__ A,
                                                  const u16* __restrict__ Bt,
                                                  u16* __restrict__ C,
                                                  u16* __restrict__ vt) {
  __shared__ u16 As[128 * 32];
  __shared__ u16 Bs[128 * 32];
  const int m0 = blockIdx.y * 128, n0 = blockIdx.x * 128;
  const int tid = threadIdx.x, w = tid >> 6, lane = tid & 63;
  const int q = lane >> 4, r = lane & 15;
  const int wm = (w >> 1) * 64, wn = (w & 1) * 64;
  const int bo0 = w * 2048 + lane * 16;
  const int row0 = bo0 >> 6, col0 = (bo0 & 63) >> 1;
  const int bo1 = bo0 + 1024;
  const int row1 = bo1 >> 6, col1 = (bo1 & 63) >> 1;
  f32x4 acc[4][4] = {};
  for (int kt = 0; kt < 256; kt += 32) {
    __syncthreads();
    gl_lds16(A + (m0 + row0) * 256 + kt + col0, As + w * 1024);
    gl_lds16(A + (m0 + row1) * 256 + kt + col1, As + w * 1024 + 512);
    gl_lds16(Bt + (n0 + row0) * 256 + kt + col0, Bs + w * 1024);
    gl_lds16(Bt + (n0 + row1) * 256 + kt + col1, Bs + w * 1024 + 512);
    __syncthreads();
    bf16x8 af[4], bf[4];
#pragma unroll
    for (int mb = 0; mb < 4; ++mb) af[mb] = *(const bf16x8*)(As + (wm + mb * 16 + r) * 32 + q * 8);
#pragma unroll
    for (int nb = 0; nb < 4; ++nb) bf[nb] = *(const bf16x8*)(Bs + (wn + nb * 16 + r) * 32 + q * 8);
#pragma unroll
    for (int mb = 0; mb < 4; ++mb)
#pragma unroll
      for (int nb = 0; nb < 4; ++nb)
        acc[mb][nb] = __builtin_amdgcn_mfma_f32_16x16x32_bf16(af[mb], bf[nb], acc[mb][nb], 0, 0, 0);
  }
  if (n0 < 4096) {
#pragma unroll
    for (int mb = 0; mb < 4; ++mb)
#pragma unroll
      for (int nb = 0; nb < 4; ++nb) {
        const int nn = n0 + wn + nb * 16 + r;
#pragma unroll
        for (int reg = 0; reg < 4; ++reg) {
          const int mm = m0 + wm + mb * 16 + q * 4 + reg;
          C[(size_t)mm * 6144 + nn] = f2bf(acc[mb][nb][reg]);
        }
      }
  } else {
    // V: transposed into vt (b,h,d,t); 4 consecutive tokens pack into one 8B store
#pragma unroll
    for (int mb = 0; mb < 4; ++mb)
#pragma unroll
      for (int nb = 0; nb < 4; ++nb) {
        const int hd = n0 - 4096 + wn + nb * 16 + r;     // h*256+d
        const int mm0 = m0 + wm + mb * 16 + q * 4;       // base token, 4 consecutive
        const int bb = mm0 >> 10, t = mm0 & 1023;
        uint2 val;
        val.x = (uint32_t)f2bf(acc[mb][nb][0]) | ((uint32_t)f2bf(acc[mb][nb][1]) << 16);
        val.y = (uint32_t)f2bf(acc[mb][nb][2]) | ((uint32_t)f2bf(acc[mb][nb][3]) << 16);
        *(uint2*)(vt + ((size_t)(bb * 2048 + hd)) * 1024 + t) = val;
      }
  }
}

// ---------------- fused flash attention (S^T / O^T, 32 q-rows/wave, fixed-ref softmax) ---
// R6 body (known-good): loads between barriers, NO register prefetch (spills — see R7).
__global__ __launch_bounds__(256, 2) void k_attn(const u16* __restrict__ qkv,
                                                 const u16* __restrict__ vt,
                                                 u16* __restrict__ att) {
  __shared__ u16 smem[17152];   // K frag [0,8192) | V frag [8192,16384) | Os overlay
  const int blk = blockIdx.x;
  const int qt = blk >> 6, bh = blk & 63;       // bh-major: XCD = h -> L2 chunk sharing
  const int b = bh >> 3, h = bh & 7;
  const int tid = threadIdx.x, w = tid >> 6, lane = tid & 63;
  const int q = lane >> 4, r = lane & 15;
  const int t0 = qt * 128 + w * 32;

  const u16* QgA = qkv + ((size_t)(b * 1024 + t0 + r)) * 6144 + h * 256;
  const u16* QgB = QgA + (size_t)16 * 6144;
  bf16x8 qfA[8], qfB[8];
#pragma unroll
  for (int kc = 0; kc < 8; ++kc) {
    qfA[kc] = *(const bf16x8*)(QgA + kc * 32 + q * 8);
    qfB[kc] = *(const bf16x8*)(QgB + kc * 32 + q * 8);
  }

  float lA = 0.0f, lB = 0.0f;
  f32x4 oA[16] = {}, oB[16] = {};

  const u16* Kg = qkv + (size_t)b * 1024 * 6144 + 2048 + h * 256;
  const u16* Vg = vt + (size_t)(b * 8 + h) * 256 * 1024;

  const int kc_s = (tid & 31) >> 2, kq_s = tid & 3;
  const int db_s = tid >> 4, vr_s = tid & 15;

  for (int sc = 0; sc < 1024; sc += 32) {
    __syncthreads();
    {
      uint4 kv[4];
#pragma unroll
      for (int p = 0; p < 4; ++p) {
        int key = p * 8 + (tid >> 5);
        kv[p] = *(const uint4*)(Kg + (size_t)(sc + key) * 6144 + (tid & 31) * 8);
      }
#pragma unroll
      for (int p = 0; p < 4; ++p) {
        int key = p * 8 + (tid >> 5);
        int sb = key >> 4, kr = key & 15;
        int unit = (kc_s * 2 + sb) * 64 + kq_s * 16 + ((kr + kq_s + kc_s * 4) & 15);
        *(uint4*)(smem + unit * 8) = kv[p];
      }
    }
    {
      uint4 vv[4];
#pragma unroll
      for (int p = 0; p < 4; ++p)
        vv[p] = *(const uint4*)(Vg + (size_t)tid * 1024 + sc + p * 8);
#pragma unroll
      for (int p = 0; p < 4; ++p) {
        int unit = db_s * 64 + p * 16 + ((vr_s + p) & 15);
        *(uint4*)(smem + 8192 + unit * 8) = vv[p];
      }
    }
    __syncthreads();

    f32x4 s0A = {}, s1A = {}, s0B = {}, s1B = {};
#pragma unroll
    for (int kc = 0; kc < 8; ++kc) {
      bf16x8 k0 = *(const bf16x8*)(smem + ((kc * 2 + 0) * 64 + q * 16 + ((r + q + kc * 4) & 15)) * 8);
      bf16x8 k1 = *(const bf16x8*)(smem + ((kc * 2 + 1) * 64 + q * 16 + ((r + q + kc * 4) & 15)) * 8);
      s0A = __builtin_amdgcn_mfma_f32_16x16x32_bf16(k0, qfA[kc], s0A, 0, 0, 0);
      s1A = __builtin_amdgcn_mfma_f32_16x16x32_bf16(k1, qfA[kc], s1A, 0, 0, 0);
      s0B = __builtin_amdgcn_mfma_f32_16x16x32_bf16(k0, qfB[kc], s0B, 0, 0, 0);
      s1B = __builtin_amdgcn_mfma_f32_16x16x32_bf16(k1, qfB[kc], s1B, 0, 0, 0);
    }

    union { bf16x8 v; u16 e[8]; } pfA, pfB;
    {
      float pa[4], pb[4];
#pragma unroll
      for (int reg = 0; reg < 4; ++reg) {
        pa[reg] = exp2f(s0A[reg] * LOG2E);
        pb[reg] = exp2f(s1A[reg] * LOG2E);
        lA += pa[reg] + pb[reg];
      }
      uint32_t pk[4];
#pragma unroll
      for (int reg = 0; reg < 4; ++reg)
        pk[reg] = (uint32_t)f2bf(pa[reg]) | ((uint32_t)f2bf(pb[reg]) << 16);
      const int srcA = ((q & 1) << 5) + r, srcB = srcA + 16;
      uint32_t tt[8];
#pragma unroll
      for (int reg = 0; reg < 4; ++reg) tt[reg] = (uint32_t)__shfl((int)pk[reg], srcA);
#pragma unroll
      for (int reg = 0; reg < 4; ++reg) tt[4 + reg] = (uint32_t)__shfl((int)pk[reg], srcB);
      const bool hi = (q >= 2);
#pragma unroll
      for (int j = 0; j < 8; ++j)
        pfA.e[j] = hi ? (u16)(tt[j] >> 16) : (u16)(tt[j] & 0xffffu);
    }
    {
      float pa[4], pb[4];
#pragma unroll
      for (int reg = 0; reg < 4; ++reg) {
        pa[reg] = exp2f(s0B[reg] * LOG2E);
        pb[reg] = exp2f(s1B[reg] * LOG2E);
        lB += pa[reg] + pb[reg];
      }
      uint32_t pk[4];
#pragma unroll
      for (int reg = 0; reg < 4; ++reg)
        pk[reg] = (uint32_t)f2bf(pa[reg]) | ((uint32_t)f2bf(pb[reg]) << 16);
      const int srcA = ((q & 1) << 5) + r, srcB = srcA + 16;
      uint32_t tt[8];
#pragma unroll
      for (int reg = 0; reg < 4; ++reg) tt[reg] = (uint32_t)__shfl((int)pk[reg], srcA);
#pragma unroll
      for (int reg = 0; reg < 4; ++reg) tt[4 + reg] = (uint32_t)__shfl((int)pk[reg], srcB);
      const bool hi = (q >= 2);
#pragma unroll
      for (int j = 0; j < 8; ++j)
        pfB.e[j] = hi ? (u16)(tt[j] >> 16) : (u16)(tt[j] & 0xffffu);
    }

#pragma unroll
    for (int db = 0; db < 16; ++db) {
      bf16x8 vf = *(const bf16x8*)(smem + 8192 + (db * 64 + q * 16 + ((r + q) & 15)) * 8);
      oA[db] = __builtin_amdgcn_mfma_f32_16x16x32_bf16(vf, pfA.v, oA[db], 0, 0, 0);
      oB[db] = __builtin_amdgcn_mfma_f32_16x16x32_bf16(vf, pfB.v, oB[db], 0, 0, 0);
    }
  }

  lA += __shfl_xor(lA, 16); lA += __shfl_xor(lA, 32);
  lB += __shfl_xor(lB, 16); lB += __shfl_xor(lB, 32);
  float rlA = 1.0f / lA, rlB = 1.0f / lB;

  __syncthreads();
  u16* Os = smem + w * 4288;
#pragma unroll
  for (int pass = 0; pass < 2; ++pass) {
    const f32x4* o = pass ? oB : oA;
    const float rl = pass ? rlB : rlA;
    const int tb = t0 + pass * 16;
    __syncthreads();
#pragma unroll
    for (int db = 0; db < 16; ++db) {
      uint32_t lo = (uint32_t)f2bf(o[db][0] * rl) | ((uint32_t)f2bf(o[db][1] * rl) << 16);
      uint32_t hi2 = (uint32_t)f2bf(o[db][2] * rl) | ((uint32_t)f2bf(o[db][3] * rl) << 16);
      uint2 val; val.x = lo; val.y = hi2;
      *(uint2*)(Os + r * 268 + db * 16 + q * 4) = val;
    }
    asm volatile("s_waitcnt lgkmcnt(0)" ::: "memory");
    u16* Ag = att + ((size_t)(b * 1024 + tb)) * 2048 + h * 256;
#pragma unroll
    for (int p = 0; p < 8; ++p) {
      int idx = (p * 64 + lane) * 8;
      int row = idx >> 8, col = idx & 255;
      *(uint4*)(Ag + (size_t)row * 2048 + col) = *(uint4*)(Os + row * 268 + col);
    }
  }
}

// ---------------- unify GEMM + bias (64x64 tiles, 512 blocks = 2/CU) ----------------
__global__ __launch_bounds__(256) void k_gemm_out(const u16* __restrict__ A,
                                                  const u16* __restrict__ Bt,
                                                  const float* __restrict__ bu,
                                                  float* __restrict__ C) {
  __shared__ u16 As[64 * 32];
  __shared__ u16 Bs[64 * 32];
  const int m0 = blockIdx.y * 64, n0 = blockIdx.x * 64;
  const int tid = threadIdx.x, w = tid >> 6, lane = tid & 63;
  const int q = lane >> 4, r = lane & 15;
  const int wm = (w >> 1) * 32, wn = (w & 1) * 32;
  const int bo = w * 1024 + lane * 16;
  const int rw = bo >> 6, cl = (bo & 63) >> 1;
  f32x4 acc[2][2] = {};
  for (int kt = 0; kt < 2048; kt += 32) {
    __syncthreads();
    gl_lds16(A + (size_t)(m0 + rw) * 2048 + kt + cl, As + w * 512);
    gl_lds16(Bt + (size_t)(n0 + rw) * 2048 + kt + cl, Bs + w * 512);
    __syncthreads();
    bf16x8 af[2], bf[2];
#pragma unroll
    for (int mb = 0; mb < 2; ++mb) af[mb] = *(const bf16x8*)(As + (wm + mb * 16 + r) * 32 + q * 8);
#pragma unroll
    for (int nb = 0; nb < 2; ++nb) bf[nb] = *(const bf16x8*)(Bs + (wn + nb * 16 + r) * 32 + q * 8);
#pragma unroll
    for (int mb = 0; mb < 2; ++mb)
#pragma unroll
      for (int nb = 0; nb < 2; ++nb)
        acc[mb][nb] = __builtin_amdgcn_mfma_f32_16x16x32_bf16(af[mb], bf[nb], acc[mb][nb], 0, 0, 0);
  }
  float bias[2];
#pragma unroll
  for (int nb = 0; nb < 2; ++nb) bias[nb] = bu[n0 + wn + nb * 16 + r];
#pragma unroll
  for (int mb = 0; mb < 2; ++mb)
#pragma unroll
    for (int nb = 0; nb < 2; ++nb) {
      const int nn = n0 + wn + nb * 16 + r;
#pragma unroll
      for (int reg = 0; reg < 4; ++reg) {
        const int mm = m0 + wm + mb * 16 + q * 4 + reg;
        C[(size_t)mm * 256 + nn] = acc[mb][nb][reg] + bias[nb];
      }
    }
}

extern "C" void kernel_launch(void* const* d_in, const int* in_sizes, int n_in,
                              void* d_out, int out_size, void* d_ws, size_t ws_size,
                              hipStream_t stream) {
  const float* x  = (const float*)d_in[0];
  const float* Wq = (const float*)d_in[1];
  const float* Wk = (const float*)d_in[2];
  const float* Wv = (const float*)d_in[3];
  const float* Wu = (const float*)d_in[4];
  const float* bu = (const float*)d_in[5];
  float* outp = (float*)d_out;

  char* ws = (char*)d_ws;
  u16* qkv   = (u16*)(ws);                          // 100663296 (V third unused)
  u16* vt    = (u16*)(ws + 100663296);              // 33554432
  u16* attb  = (u16*)(ws + 134217728);              // 33554432
  u16* wqkvt = (u16*)(ws + 167772160);              // 3145728
  u16* wut   = (u16*)(ws + 170917888);              // 1048576
  u16* xb    = (u16*)(ws + 171966464);              // 4194304
  (void)in_sizes; (void)n_in; (void)out_size; (void)ws_size;

  dim3 blk(256);
  k_prep<<<dim3(2560), blk, 0, stream>>>(x, Wq, Wk, Wv, Wu, xb, wqkvt, wut);
  k_gemm_qkv<<<dim3(48, 64), blk, 0, stream>>>(xb, wqkvt, qkv, vt);
  k_attn<<<dim3(512), blk, 0, stream>>>(qkv, vt, attb);
  k_gemm_out<<<dim3(4, 128), blk, 0, stream>>>(attb, wut, bu, outp);
}